// Round 8
// baseline (218.765 us; speedup 1.0000x reference)
//
#include <hip/hip_runtime.h>

#define FEAT_H 32
#define FEAT_W 110
#define NCELL (FEAT_H * FEAT_W) /* 3520 */
#define STRIDEPX 16
#define NB 8
#define NG 32
#define NANC 36
#define NC 4
#define A_TOTAL (NCELL * NANC) /* 126720 */
#define BLK 256
#define CHUNKS (A_TOTAL / BLK) /* 495 */
#define NSLICE 4
#define CPS (NCELL / NSLICE) /* 880 cells per slice */
#define G2 1024              /* k_main grid: 4 blocks/CU target */
#define CB (G2 / NB)         /* 128 chunk stride per image */
#define MAXSLOTS 4           /* ceil(495/128) */

__device__ __forceinline__ float smooth_l1(float x) {
    float ax = fabsf(x);
    return ax < 1.f ? 0.5f * ax * ax : ax - 0.5f;
}

// ws: colpart[1024] u64 @0 (8 KB), acc[8] f32 @8192, done u32 @8224.

// Column-max pass, cell-major (R7, unchanged: anch4[t] here is inner-loop
// wave-UNIFORM -> LDS broadcast, conflict-free). Zeroes acc/done.
__global__ __launch_bounds__(BLK) void k_colpass(
    const float* __restrict__ gt_boxes, const int* __restrict__ gt_valid,
    const float* __restrict__ anchors, unsigned long long* __restrict__ colpart,
    float* __restrict__ acc, unsigned* __restrict__ done) {
#pragma clang fp contract(off)
    __shared__ float4 anch4[NANC];
    __shared__ float aarea[NANC];
    __shared__ unsigned long long wbest[BLK / 64];
    const int tid = threadIdx.x;
    if (blockIdx.x == 0) { // ws is 0xAA-poisoned each call
        if (tid < 8) acc[tid] = 0.f;
        if (tid == 8) *done = 0u;
    }
    const int bg = blockIdx.x >> 2;   // column (b*NG+g) 0..255
    const int slice = blockIdx.x & 3;
    if (tid < NANC) {
        const float* ap = anchors + tid * 9;
        const float4 v = make_float4(ap[0], ap[1], ap[2], ap[3]);
        anch4[tid] = v;
        aarea[tid] = (v.z - v.x + 1.f) * (v.w - v.y + 1.f);
    }
    __syncthreads();
    unsigned long long best = 0ull;
    if (gt_valid[bg]) {
        const float g0 = gt_boxes[bg * 4 + 0], g1 = gt_boxes[bg * 4 + 1];
        const float g2 = gt_boxes[bg * 4 + 2], g3 = gt_boxes[bg * 4 + 3];
        const float ag = (g2 - g0 + 1.f) * (g3 - g1 + 1.f);
        const int cend = (slice + 1) * CPS;
        for (int c = slice * CPS + tid; c < cend; c += BLK) {
            const float sx = (float)((c % FEAT_W) * STRIDEPX);
            const float sy = (float)((c / FEAT_W) * STRIDEPX);
            int a = c * NANC;
#pragma unroll 4
            for (int t = 0; t < NANC; ++t, ++a) {
                const float4 av = anch4[t];          // wave-uniform broadcast
                const float r0 = sx + av.x, r1 = sy + av.y;
                const float r2 = sx + av.z, r3 = sy + av.w;
                const float xx1 = fmaxf(r0, g0), yy1 = fmaxf(r1, g1);
                const float xx2 = fminf(r2, g2), yy2 = fminf(r3, g3);
                const float iw = fmaxf(xx2 - xx1 + 1.f, 0.f);
                const float ih = fmaxf(yy2 - yy1 + 1.f, 0.f);
                const float inter = iw * ih;
                const float iou =
                    inter * __builtin_amdgcn_rcpf(aarea[t] + ag - inter);
                const unsigned long long p =
                    ((unsigned long long)__float_as_uint(iou) << 32) |
                    (unsigned long long)(0xFFFFFFFFu - (unsigned)a);
                if (p > best) best = p;
            }
        }
    }
    for (int off = 32; off; off >>= 1) {
        unsigned long long o = __shfl_down(best, off, 64);
        if (o > best) best = o;
    }
    if ((tid & 63) == 0) wbest[tid >> 6] = best;
    __syncthreads();
    if (tid == 0) {
        for (int w = 1; w < BLK / 64; ++w)
            if (wbest[w] > best) best = wbest[w];
        colpart[blockIdx.x] = best; // layout: bg*4 + slice, unique writer
    }
}

// Row pass + loss. 1024 blocks, b = blk/CB, chunks c0 + k*CB (<=4).
// cls pipelined one chunk ahead (R3's win); b2d/b3d loads exec-masked under
// fg (R7's unconditional prefetch tripled FETCH and raised VGPR to 132 for
// zero gain). Anchor box LDS is SoA b32 (<=2-way, free) instead of per-lane
// float4 (8-way conflicted).
__global__ __launch_bounds__(BLK) void k_main(
    const float* __restrict__ cls, const float* __restrict__ bbox_2d,
    const float* __restrict__ bbox_3d, const float* __restrict__ gt_boxes,
    const float* __restrict__ gt_3d, const int* __restrict__ gt_labels,
    const int* __restrict__ gt_valid, const float* __restrict__ anchors,
    const float* __restrict__ means, const float* __restrict__ stds,
    const unsigned long long* __restrict__ colpart, float* __restrict__ acc,
    unsigned* __restrict__ done, float* __restrict__ out) {
#pragma clang fp contract(off)
    __shared__ float ax0_s[NANC], ay0_s[NANC], ax1_s[NANC], ay1_s[NANC];
    __shared__ float anch9[NANC * 9];
    __shared__ float4 gtb4_s[NG];
    __shared__ float ags_s[NG];
    __shared__ float gt3_s[NG * 7];
    __shared__ int lbl_s[NG];
    __shared__ int bag_s[NG], forceg_s[NG];
    __shared__ float mean_s[11], rstd_s[11];
    __shared__ unsigned vmask_s;
    __shared__ float red[5][BLK / 64];
    __shared__ int fixmap[MAXSLOTS * BLK]; // 4 KB

    const int tid = threadIdx.x;
    const int b = blockIdx.x / CB;
    const int c0 = blockIdx.x % CB;

    // ---- staging ----
    for (int i = tid; i < NANC * 9; i += BLK) anch9[i] = anchors[i];
    if (tid < NANC) {
        const float* ap = anchors + tid * 9;
        ax0_s[tid] = ap[0]; ay0_s[tid] = ap[1];
        ax1_s[tid] = ap[2]; ay1_s[tid] = ap[3];
    }
    for (int i = tid; i < NG * 7; i += BLK) gt3_s[i] = gt_3d[b * NG * 7 + i];
    int myval = 0;
    if (tid < NG) {
        const float4 q = ((const float4*)gt_boxes)[b * NG + tid];
        gtb4_s[tid] = q;
        ags_s[tid] = (q.z - q.x + 1.f) * (q.w - q.y + 1.f);
        lbl_s[tid] = gt_labels[b * NG + tid];
        myval = gt_valid[b * NG + tid];
        unsigned long long p = colpart[(b * NG + tid) * 4 + 0];
        for (int s = 1; s < 4; ++s) {
            const unsigned long long q2 = colpart[(b * NG + tid) * 4 + s];
            if (q2 > p) p = q2;
        }
        const float gbest = __uint_as_float((unsigned)(p >> 32));
        bag_s[tid] = myval ? (int)(0xFFFFFFFFu - (unsigned)(p & 0xFFFFFFFFull)) : 0;
        forceg_s[tid] = (myval && gbest >= 0.35f) ? 1 : 0;
    }
    unsigned long long bal = __ballot(tid < NG && myval);
    if (tid == 0) vmask_s = (unsigned)bal;
    if (tid < 11) { mean_s[tid] = means[tid]; rstd_s[tid] = 1.0f / stds[tid]; }
    const int nslots = (CHUNKS - 1 - c0) / CB + 1; // <= 4
    for (int i = tid; i < nslots * BLK; i += BLK) fixmap[i] = -1;
    __syncthreads();
    if (tid == 0) {
        // ascending-g serial build: last-update-wins for agt, OR for force
        // (exact jax .at[ba].set / .at[ba].max gather-before-scatter)
        for (int g = 0; g < NG; ++g) {
            const int ba = bag_s[g];
            const int cb = ba >> 8; // chunk index (BLK=256)
            if (cb % CB == c0) {
                const int k = (cb - c0) / CB;
                const int idx = k * BLK + (ba & 255);
                const int e = fixmap[idx];
                const int anyf = ((e >= 0) ? (e & 0x40000000) : 0) |
                                 (forceg_s[g] ? 0x40000000 : 0);
                const int code = forceg_s[g] ? g : 32; // 32 = keep agt_orig
                fixmap[idx] = anyf | code;
            }
        }
    }
    __syncthreads();
    const unsigned vmask = vmask_s;

    // ---- main loop (cls pipelined one chunk ahead) ----
    float sum_ce = 0.f, sum_act = 0.f, sum_fg = 0.f, sum_2d = 0.f, sum_3d = 0.f;
    const size_t bbase = (size_t)b * A_TOTAL;

    int chunk = c0;
    float4 cv = *(const float4*)(cls + (bbase + (size_t)chunk * BLK + tid) * NC);
    for (int k = 0; k < nslots; ++k) {
        float4 cv_next = make_float4(0.f, 0.f, 0.f, 0.f);
        if (k + 1 < nslots)
            cv_next = *(const float4*)(cls +
                        (bbase + (size_t)(chunk + CB) * BLK + tid) * NC);

        const int a = chunk * BLK + tid;
        const int t = a % NANC;
        const int cell = a / NANC;
        const float sx = (float)((cell % FEAT_W) * STRIDEPX);
        const float sy = (float)((cell / FEAT_W) * STRIDEPX);
        const float r0 = sx + ax0_s[t], r1 = sy + ay0_s[t];
        const float r2 = sx + ax1_s[t], r3 = sy + ay1_s[t];
        const float ar = (r2 - r0 + 1.f) * (r3 - r1 + 1.f);

        // grouped argmax: 4 groups of 8, scalar regs; strict '>' ascending
        // preserves first-occurrence exactly (incl. all-invalid -> 0)
        float m0 = -1.f, m1 = -1.f, m2 = -1.f, m3 = -1.f;
        int i0 = 0, i1 = 8, i2 = 16, i3 = 24;
#pragma unroll
        for (int g = 0; g < NG; ++g) {
            const float4 q = gtb4_s[g];              // wave-uniform broadcast
            const float xx1 = fmaxf(r0, q.x), yy1 = fmaxf(r1, q.y);
            const float xx2 = fminf(r2, q.z), yy2 = fminf(r3, q.w);
            const float iw = fmaxf(xx2 - xx1 + 1.f, 0.f);
            const float ih = fmaxf(yy2 - yy1 + 1.f, 0.f);
            const float inter = iw * ih;
            float iou = inter * __builtin_amdgcn_rcpf(ar + ags_s[g] - inter);
            iou = ((vmask >> g) & 1u) ? iou : -1.0f;
            if (g < 8)       { if (iou > m0) { m0 = iou; i0 = g; } }
            else if (g < 16) { if (iou > m1) { m1 = iou; i1 = g; } }
            else if (g < 24) { if (iou > m2) { m2 = iou; i2 = g; } }
            else             { if (iou > m3) { m3 = iou; i3 = g; } }
        }
        float best = m0; int agt = i0;
        if (m1 > best) { best = m1; agt = i1; }
        if (m2 > best) { best = m2; agt = i2; }
        if (m3 > best) { best = m3; agt = i3; }

        bool fg = best >= 0.5f;
        const int agt_orig = agt;
        const int f = fixmap[k * BLK + tid];
        if (f >= 0) {
            if (f & 0x40000000) fg = true;
            const int code = f & 63;
            agt = (code == 32) ? agt_orig : code;
        }
        const bool bgm = (!fg) && (best < 0.5f) && (best >= 0.0f);
        const float active = (fg || bgm) ? 1.f : 0.f;
        const int lbl = fg ? lbl_s[agt] : 0;

        const float mx = fmaxf(fmaxf(cv.x, cv.y), fmaxf(cv.z, cv.w));
        const float se = __expf(cv.x - mx) + __expf(cv.y - mx) +
                         __expf(cv.z - mx) + __expf(cv.w - mx);
        const float lse = mx + __logf(se);
        const float csel = (lbl == 0) ? cv.x : (lbl == 1) ? cv.y
                         : (lbl == 2) ? cv.z : cv.w;
        sum_ce += (lse - csel) * active;
        sum_act += active;

        if (fg) { // rare (~1-2% of anchors): exec-masked gathers are fine here
            sum_fg += 1.f;
            const float w = r2 - r0 + 1.f, h = r3 - r1 + 1.f;
            const float rw = __builtin_amdgcn_rcpf(w);
            const float rh = __builtin_amdgcn_rcpf(h);
            const float cx = r0 + 0.5f * w, cy = r1 + 0.5f * h;
            const float4 Gq = gtb4_s[agt];
            const float gw = Gq.z - Gq.x + 1.f, gh = Gq.w - Gq.y + 1.f;
            const float gcx = Gq.x + 0.5f * gw, gcy = Gq.y + 0.5f * gh;
            float t2[4];
            t2[0] = (gcx - cx) * rw;
            t2[1] = (gcy - cy) * rh;
            t2[2] = __logf(gw * rw);
            t2[3] = __logf(gh * rh);
            const float4 b2 = *(const float4*)(bbox_2d + (bbase + a) * 4);
            const float b2v[4] = {b2.x, b2.y, b2.z, b2.w};
            float l2 = 0.f;
            for (int j = 0; j < 4; ++j)
                l2 += smooth_l1(b2v[j] - (t2[j] - mean_s[j]) * rstd_s[j]);
            sum_2d += l2;
            const float* q3p = &gt3_s[agt * 7];
            const float* b3 = bbox_3d + (bbase + a) * 7;
            float t3[7];
            t3[0] = (q3p[0] - cx) * rw;
            t3[1] = (q3p[1] - cy) * rh;
            t3[2] = q3p[2] - anch9[t * 9 + 4];
            t3[3] = __logf(q3p[3] * __builtin_amdgcn_rcpf(anch9[t * 9 + 5]));
            t3[4] = __logf(q3p[4] * __builtin_amdgcn_rcpf(anch9[t * 9 + 6]));
            t3[5] = __logf(q3p[5] * __builtin_amdgcn_rcpf(anch9[t * 9 + 7]));
            t3[6] = q3p[6] - anch9[t * 9 + 8];
            float l3 = 0.f;
            for (int j = 0; j < 7; ++j)
                l3 += smooth_l1(b3[j] - (t3[j] - mean_s[4 + j]) * rstd_s[4 + j]);
            sum_3d += l3;
        }
        cv = cv_next;
        chunk += CB;
    }

    // ---- block reduce -> 5 atomics; last block finishes ----
    float vals[5] = {sum_ce, sum_act, sum_fg, sum_2d, sum_3d};
#pragma unroll
    for (int j = 0; j < 5; ++j) {
        float v = vals[j];
        for (int off = 32; off; off >>= 1) v += __shfl_down(v, off, 64);
        if ((tid & 63) == 0) red[j][tid >> 6] = v;
    }
    __syncthreads();
    if (tid == 0) {
        for (int j = 0; j < 5; ++j) {
            float s = 0.f;
            for (int w = 0; w < BLK / 64; ++w) s += red[j][w];
            atomicAdd(&acc[j], s);
        }
        __threadfence();
        const unsigned old = atomicAdd(done, 1u);
        if (old == G2 - 1) {
            const float a0 = atomicAdd(&acc[0], 0.f);
            const float a1 = atomicAdd(&acc[1], 0.f);
            const float a2 = atomicAdd(&acc[2], 0.f);
            const float a3 = atomicAdd(&acc[3], 0.f);
            const float a4 = atomicAdd(&acc[4], 0.f);
            const float nact = fmaxf(a1, 1.f);
            const float nfg = fmaxf(a2, 1.f);
            out[0] = a0 / nact + a3 / nfg + a4 / nfg;
        }
    }
}

extern "C" void kernel_launch(void* const* d_in, const int* in_sizes, int n_in,
                              void* d_out, int out_size, void* d_ws, size_t ws_size,
                              hipStream_t stream) {
    const float* cls      = (const float*)d_in[0];
    const float* bbox_2d  = (const float*)d_in[1];
    const float* bbox_3d  = (const float*)d_in[2];
    const float* gt_boxes = (const float*)d_in[3];
    const float* gt_3d    = (const float*)d_in[4];
    const int*   gt_labels= (const int*)d_in[5];
    const int*   gt_valid = (const int*)d_in[6];
    const float* anchors  = (const float*)d_in[7];
    const float* means    = (const float*)d_in[8];
    const float* stds     = (const float*)d_in[9];

    unsigned long long* colpart = (unsigned long long*)d_ws;  // 8 KB @0
    float* acc = (float*)((char*)d_ws + 8192);
    unsigned* done = (unsigned*)((char*)d_ws + 8192 + 32);
    float* out = (float*)d_out;

    k_colpass<<<256 * NSLICE, BLK, 0, stream>>>(gt_boxes, gt_valid, anchors,
                                                colpart, acc, done);
    k_main<<<G2, BLK, 0, stream>>>(cls, bbox_2d, bbox_3d, gt_boxes, gt_3d,
                                   gt_labels, gt_valid, anchors, means, stds,
                                   colpart, acc, done, out);
}

// Round 9
// 173.502 us; speedup vs baseline: 1.2609x; 1.2609x over previous
//
#include <hip/hip_runtime.h>

#define FEAT_H 32
#define FEAT_W 110
#define NCELL (FEAT_H * FEAT_W) /* 3520 */
#define STRIDEPX 16
#define NB 8
#define NG 32
#define NANC 36
#define NC 4
#define A_TOTAL (NCELL * NANC) /* 126720 */
#define BLK 256
#define CHUNKS (A_TOTAL / BLK) /* 495 */
#define NSLICE 2
#define CPS (NCELL / NSLICE) /* 1760 cells per slice */
#define GCOL (256 * NSLICE)  /* 512 colpass blocks */
#define G2 256               /* k_main grid: 1 block/CU — minimize WG count */
#define CB (G2 / NB)         /* 32 chunk stride per image */
#define MAXSLOTS 16          /* ceil(495/32) */

__device__ __forceinline__ float smooth_l1(float x) {
    float ax = fabsf(x);
    return ax < 1.f ? 0.5f * ax * ax : ax - 0.5f;
}

// ws: colpart[512] u64 @0 (4 KB), acc[8] f32 @8192, done u32 @8224.

// Column-max pass, cell-major (conflict-free wave-uniform anch reads).
// 512 blocks: column (b,g) x 2 slices. Zeroes acc/done for k_main.
__global__ __launch_bounds__(BLK) void k_colpass(
    const float* __restrict__ gt_boxes, const int* __restrict__ gt_valid,
    const float* __restrict__ anchors, unsigned long long* __restrict__ colpart,
    float* __restrict__ acc, unsigned* __restrict__ done) {
#pragma clang fp contract(off)
    __shared__ float4 anch4[NANC];
    __shared__ float aarea[NANC];
    __shared__ unsigned long long wbest[BLK / 64];
    const int tid = threadIdx.x;
    if (blockIdx.x == 0) { // ws is 0xAA-poisoned each call
        if (tid < 8) acc[tid] = 0.f;
        if (tid == 8) *done = 0u;
    }
    const int bg = blockIdx.x >> 1;   // column (b*NG+g) 0..255
    const int slice = blockIdx.x & 1;
    if (tid < NANC) {
        const float* ap = anchors + tid * 9;
        const float4 v = make_float4(ap[0], ap[1], ap[2], ap[3]);
        anch4[tid] = v;
        aarea[tid] = (v.z - v.x + 1.f) * (v.w - v.y + 1.f);
    }
    __syncthreads();
    unsigned long long best = 0ull;
    if (gt_valid[bg]) {
        const float g0 = gt_boxes[bg * 4 + 0], g1 = gt_boxes[bg * 4 + 1];
        const float g2 = gt_boxes[bg * 4 + 2], g3 = gt_boxes[bg * 4 + 3];
        const float ag = (g2 - g0 + 1.f) * (g3 - g1 + 1.f);
        const int cend = (slice + 1) * CPS;
        for (int c = slice * CPS + tid; c < cend; c += BLK) {
            const float sx = (float)((c % FEAT_W) * STRIDEPX);
            const float sy = (float)((c / FEAT_W) * STRIDEPX);
            int a = c * NANC;
#pragma unroll 4
            for (int t = 0; t < NANC; ++t, ++a) {
                const float4 av = anch4[t];          // wave-uniform broadcast
                const float r0 = sx + av.x, r1 = sy + av.y;
                const float r2 = sx + av.z, r3 = sy + av.w;
                const float xx1 = fmaxf(r0, g0), yy1 = fmaxf(r1, g1);
                const float xx2 = fminf(r2, g2), yy2 = fminf(r3, g3);
                const float iw = fmaxf(xx2 - xx1 + 1.f, 0.f);
                const float ih = fmaxf(yy2 - yy1 + 1.f, 0.f);
                const float inter = iw * ih;
                const float iou =
                    inter * __builtin_amdgcn_rcpf(aarea[t] + ag - inter);
                const unsigned long long p =
                    ((unsigned long long)__float_as_uint(iou) << 32) |
                    (unsigned long long)(0xFFFFFFFFu - (unsigned)a);
                if (p > best) best = p;
            }
        }
    }
    for (int off = 32; off; off >>= 1) {
        unsigned long long o = __shfl_down(best, off, 64);
        if (o > best) best = o;
    }
    if ((tid & 63) == 0) wbest[tid >> 6] = best;
    __syncthreads();
    if (tid == 0) {
        for (int w = 1; w < BLK / 64; ++w)
            if (wbest[w] > best) best = wbest[w];
        colpart[blockIdx.x] = best; // layout: bg*2 + slice, unique writer
    }
}

// Row pass + loss. 256 blocks (1/CU), b = blk/CB, chunks c0 + k*CB (<=16).
// cls software-pipelined TWO chunks ahead (2 vmem in flight/thread makes up
// for the low 4-waves/CU TLP at this grid size).
__global__ __launch_bounds__(BLK) void k_main(
    const float* __restrict__ cls, const float* __restrict__ bbox_2d,
    const float* __restrict__ bbox_3d, const float* __restrict__ gt_boxes,
    const float* __restrict__ gt_3d, const int* __restrict__ gt_labels,
    const int* __restrict__ gt_valid, const float* __restrict__ anchors,
    const float* __restrict__ means, const float* __restrict__ stds,
    const unsigned long long* __restrict__ colpart, float* __restrict__ acc,
    unsigned* __restrict__ done, float* __restrict__ out) {
#pragma clang fp contract(off)
    __shared__ float ax0_s[NANC], ay0_s[NANC], ax1_s[NANC], ay1_s[NANC];
    __shared__ float anch9[NANC * 9];
    __shared__ float4 gtb4_s[NG];
    __shared__ float ags_s[NG];
    __shared__ float gt3_s[NG * 7];
    __shared__ int lbl_s[NG];
    __shared__ int bag_s[NG], forceg_s[NG];
    __shared__ float mean_s[11], rstd_s[11];
    __shared__ unsigned vmask_s;
    __shared__ float red[5][BLK / 64];
    __shared__ int fixmap[MAXSLOTS * BLK]; // 16 KB

    const int tid = threadIdx.x;
    const int b = blockIdx.x / CB;
    const int c0 = blockIdx.x % CB;

    // ---- staging ----
    for (int i = tid; i < NANC * 9; i += BLK) anch9[i] = anchors[i];
    if (tid < NANC) {
        const float* ap = anchors + tid * 9;
        ax0_s[tid] = ap[0]; ay0_s[tid] = ap[1];
        ax1_s[tid] = ap[2]; ay1_s[tid] = ap[3];
    }
    for (int i = tid; i < NG * 7; i += BLK) gt3_s[i] = gt_3d[b * NG * 7 + i];
    int myval = 0;
    if (tid < NG) {
        const float4 q = ((const float4*)gt_boxes)[b * NG + tid];
        gtb4_s[tid] = q;
        ags_s[tid] = (q.z - q.x + 1.f) * (q.w - q.y + 1.f);
        lbl_s[tid] = gt_labels[b * NG + tid];
        myval = gt_valid[b * NG + tid];
        unsigned long long p = colpart[(b * NG + tid) * NSLICE + 0];
        for (int s = 1; s < NSLICE; ++s) {
            const unsigned long long q2 = colpart[(b * NG + tid) * NSLICE + s];
            if (q2 > p) p = q2;
        }
        const float gbest = __uint_as_float((unsigned)(p >> 32));
        bag_s[tid] = myval ? (int)(0xFFFFFFFFu - (unsigned)(p & 0xFFFFFFFFull)) : 0;
        forceg_s[tid] = (myval && gbest >= 0.35f) ? 1 : 0;
    }
    unsigned long long bal = __ballot(tid < NG && myval);
    if (tid == 0) vmask_s = (unsigned)bal;
    if (tid < 11) { mean_s[tid] = means[tid]; rstd_s[tid] = 1.0f / stds[tid]; }
    const int nslots = (CHUNKS - 1 - c0) / CB + 1; // <= 16
    for (int i = tid; i < nslots * BLK; i += BLK) fixmap[i] = -1;
    __syncthreads();
    if (tid == 0) {
        // ascending-g serial build: last-update-wins for agt, OR for force
        // (exact jax .at[ba].set / .at[ba].max gather-before-scatter)
        for (int g = 0; g < NG; ++g) {
            const int ba = bag_s[g];
            const int cb = ba >> 8; // chunk index (BLK=256)
            if (cb % CB == c0) {
                const int k = (cb - c0) / CB;
                const int idx = k * BLK + (ba & 255);
                const int e = fixmap[idx];
                const int anyf = ((e >= 0) ? (e & 0x40000000) : 0) |
                                 (forceg_s[g] ? 0x40000000 : 0);
                const int code = forceg_s[g] ? g : 32; // 32 = keep agt_orig
                fixmap[idx] = anyf | code;
            }
        }
    }
    __syncthreads();
    const unsigned vmask = vmask_s;

    // ---- main loop (cls pipelined TWO chunks ahead) ----
    float sum_ce = 0.f, sum_act = 0.f, sum_fg = 0.f, sum_2d = 0.f, sum_3d = 0.f;
    const size_t bbase = (size_t)b * A_TOTAL;

    int chunk = c0;
    float4 cv0 = *(const float4*)(cls + (bbase + (size_t)chunk * BLK + tid) * NC);
    float4 cv1 = make_float4(0.f, 0.f, 0.f, 0.f);
    if (nslots > 1)
        cv1 = *(const float4*)(cls + (bbase + (size_t)(chunk + CB) * BLK + tid) * NC);

    for (int k = 0; k < nslots; ++k) {
        float4 cv2 = make_float4(0.f, 0.f, 0.f, 0.f);
        if (k + 2 < nslots)
            cv2 = *(const float4*)(cls +
                     (bbase + (size_t)(chunk + 2 * CB) * BLK + tid) * NC);

        const int a = chunk * BLK + tid;
        const int t = a % NANC;
        const int cell = a / NANC;
        const float sx = (float)((cell % FEAT_W) * STRIDEPX);
        const float sy = (float)((cell / FEAT_W) * STRIDEPX);
        const float r0 = sx + ax0_s[t], r1 = sy + ay0_s[t];
        const float r2 = sx + ax1_s[t], r3 = sy + ay1_s[t];
        const float ar = (r2 - r0 + 1.f) * (r3 - r1 + 1.f);

        // grouped argmax: 4 groups of 8, scalar regs; strict '>' ascending
        // preserves first-occurrence exactly (incl. all-invalid -> 0)
        float m0 = -1.f, m1 = -1.f, m2 = -1.f, m3 = -1.f;
        int i0 = 0, i1 = 8, i2 = 16, i3 = 24;
#pragma unroll
        for (int g = 0; g < NG; ++g) {
            const float4 q = gtb4_s[g];              // wave-uniform broadcast
            const float xx1 = fmaxf(r0, q.x), yy1 = fmaxf(r1, q.y);
            const float xx2 = fminf(r2, q.z), yy2 = fminf(r3, q.w);
            const float iw = fmaxf(xx2 - xx1 + 1.f, 0.f);
            const float ih = fmaxf(yy2 - yy1 + 1.f, 0.f);
            const float inter = iw * ih;
            float iou = inter * __builtin_amdgcn_rcpf(ar + ags_s[g] - inter);
            iou = ((vmask >> g) & 1u) ? iou : -1.0f;
            if (g < 8)       { if (iou > m0) { m0 = iou; i0 = g; } }
            else if (g < 16) { if (iou > m1) { m1 = iou; i1 = g; } }
            else if (g < 24) { if (iou > m2) { m2 = iou; i2 = g; } }
            else             { if (iou > m3) { m3 = iou; i3 = g; } }
        }
        float best = m0; int agt = i0;
        if (m1 > best) { best = m1; agt = i1; }
        if (m2 > best) { best = m2; agt = i2; }
        if (m3 > best) { best = m3; agt = i3; }

        bool fg = best >= 0.5f;
        const int agt_orig = agt;
        const int f = fixmap[k * BLK + tid];
        if (f >= 0) {
            if (f & 0x40000000) fg = true;
            const int code = f & 63;
            agt = (code == 32) ? agt_orig : code;
        }
        const bool bgm = (!fg) && (best < 0.5f) && (best >= 0.0f);
        const float active = (fg || bgm) ? 1.f : 0.f;
        const int lbl = fg ? lbl_s[agt] : 0;

        const float mx = fmaxf(fmaxf(cv0.x, cv0.y), fmaxf(cv0.z, cv0.w));
        const float se = __expf(cv0.x - mx) + __expf(cv0.y - mx) +
                         __expf(cv0.z - mx) + __expf(cv0.w - mx);
        const float lse = mx + __logf(se);
        const float csel = (lbl == 0) ? cv0.x : (lbl == 1) ? cv0.y
                         : (lbl == 2) ? cv0.z : cv0.w;
        sum_ce += (lse - csel) * active;
        sum_act += active;

        if (fg) { // rare: exec-masked gathers, issued only when needed
            sum_fg += 1.f;
            const float w = r2 - r0 + 1.f, h = r3 - r1 + 1.f;
            const float rw = __builtin_amdgcn_rcpf(w);
            const float rh = __builtin_amdgcn_rcpf(h);
            const float cx = r0 + 0.5f * w, cy = r1 + 0.5f * h;
            const float4 Gq = gtb4_s[agt];
            const float gw = Gq.z - Gq.x + 1.f, gh = Gq.w - Gq.y + 1.f;
            const float gcx = Gq.x + 0.5f * gw, gcy = Gq.y + 0.5f * gh;
            float t2[4];
            t2[0] = (gcx - cx) * rw;
            t2[1] = (gcy - cy) * rh;
            t2[2] = __logf(gw * rw);
            t2[3] = __logf(gh * rh);
            const float4 b2 = *(const float4*)(bbox_2d + (bbase + a) * 4);
            const float b2v[4] = {b2.x, b2.y, b2.z, b2.w};
            float l2 = 0.f;
            for (int j = 0; j < 4; ++j)
                l2 += smooth_l1(b2v[j] - (t2[j] - mean_s[j]) * rstd_s[j]);
            sum_2d += l2;
            const float* q3p = &gt3_s[agt * 7];
            const float* b3 = bbox_3d + (bbase + a) * 7;
            float t3[7];
            t3[0] = (q3p[0] - cx) * rw;
            t3[1] = (q3p[1] - cy) * rh;
            t3[2] = q3p[2] - anch9[t * 9 + 4];
            t3[3] = __logf(q3p[3] * __builtin_amdgcn_rcpf(anch9[t * 9 + 5]));
            t3[4] = __logf(q3p[4] * __builtin_amdgcn_rcpf(anch9[t * 9 + 6]));
            t3[5] = __logf(q3p[5] * __builtin_amdgcn_rcpf(anch9[t * 9 + 7]));
            t3[6] = q3p[6] - anch9[t * 9 + 8];
            float l3 = 0.f;
            for (int j = 0; j < 7; ++j)
                l3 += smooth_l1(b3[j] - (t3[j] - mean_s[4 + j]) * rstd_s[4 + j]);
            sum_3d += l3;
        }
        cv0 = cv1;
        cv1 = cv2;
        chunk += CB;
    }

    // ---- block reduce -> 5 atomics; last block finishes ----
    float vals[5] = {sum_ce, sum_act, sum_fg, sum_2d, sum_3d};
#pragma unroll
    for (int j = 0; j < 5; ++j) {
        float v = vals[j];
        for (int off = 32; off; off >>= 1) v += __shfl_down(v, off, 64);
        if ((tid & 63) == 0) red[j][tid >> 6] = v;
    }
    __syncthreads();
    if (tid == 0) {
        for (int j = 0; j < 5; ++j) {
            float s = 0.f;
            for (int w = 0; w < BLK / 64; ++w) s += red[j][w];
            atomicAdd(&acc[j], s);
        }
        __threadfence();
        const unsigned old = atomicAdd(done, 1u);
        if (old == G2 - 1) {
            const float a0 = atomicAdd(&acc[0], 0.f);
            const float a1 = atomicAdd(&acc[1], 0.f);
            const float a2 = atomicAdd(&acc[2], 0.f);
            const float a3 = atomicAdd(&acc[3], 0.f);
            const float a4 = atomicAdd(&acc[4], 0.f);
            const float nact = fmaxf(a1, 1.f);
            const float nfg = fmaxf(a2, 1.f);
            out[0] = a0 / nact + a3 / nfg + a4 / nfg;
        }
    }
}

extern "C" void kernel_launch(void* const* d_in, const int* in_sizes, int n_in,
                              void* d_out, int out_size, void* d_ws, size_t ws_size,
                              hipStream_t stream) {
    const float* cls      = (const float*)d_in[0];
    const float* bbox_2d  = (const float*)d_in[1];
    const float* bbox_3d  = (const float*)d_in[2];
    const float* gt_boxes = (const float*)d_in[3];
    const float* gt_3d    = (const float*)d_in[4];
    const int*   gt_labels= (const int*)d_in[5];
    const int*   gt_valid = (const int*)d_in[6];
    const float* anchors  = (const float*)d_in[7];
    const float* means    = (const float*)d_in[8];
    const float* stds     = (const float*)d_in[9];

    unsigned long long* colpart = (unsigned long long*)d_ws;  // 4 KB @0
    float* acc = (float*)((char*)d_ws + 8192);
    unsigned* done = (unsigned*)((char*)d_ws + 8192 + 32);
    float* out = (float*)d_out;

    k_colpass<<<GCOL, BLK, 0, stream>>>(gt_boxes, gt_valid, anchors,
                                        colpart, acc, done);
    k_main<<<G2, BLK, 0, stream>>>(cls, bbox_2d, bbox_3d, gt_boxes, gt_3d,
                                   gt_labels, gt_valid, anchors, means, stds,
                                   colpart, acc, done, out);
}

// Round 10
// 171.778 us; speedup vs baseline: 1.2735x; 1.0100x over previous
//
#include <hip/hip_runtime.h>

#define FEAT_H 32
#define FEAT_W 110
#define NCELL (FEAT_H * FEAT_W) /* 3520 */
#define STRIDEPX 16
#define NB 8
#define NG 32
#define NANC 36
#define NC 4
#define A_TOTAL (NCELL * NANC) /* 126720 */
#define BLK 256
#define CHUNKS (A_TOTAL / BLK) /* 495 */
#define NSLICE 4             /* colpass: 1024 blocks = 4/CU, latency-hiding regime */
#define CPS (NCELL / NSLICE) /* 880 cells per slice */
#define GCOL (256 * NSLICE)  /* 1024 colpass blocks */
#define G2 256               /* k_main grid: 1 block/CU — block-churn regime */
#define CB (G2 / NB)         /* 32 chunk stride per image */
#define MAXSLOTS 16          /* ceil(495/32) */

__device__ __forceinline__ float smooth_l1(float x) {
    float ax = fabsf(x);
    return ax < 1.f ? 0.5f * ax * ax : ax - 0.5f;
}

// ws: colpart[1024] u64 @0 (8 KB), acc[8] f32 @8192, done u32 @8224.

// Column-max pass, cell-major (conflict-free wave-uniform anch reads).
// 1024 blocks: column (b,g) x 4 slices — colpass is latency-bound (248->62
// serial IoUs/thread), it WANTS waves; R9's 512-block version doubled its
// time. Zeroes acc/done for k_main.
__global__ __launch_bounds__(BLK) void k_colpass(
    const float* __restrict__ gt_boxes, const int* __restrict__ gt_valid,
    const float* __restrict__ anchors, unsigned long long* __restrict__ colpart,
    float* __restrict__ acc, unsigned* __restrict__ done) {
#pragma clang fp contract(off)
    __shared__ float4 anch4[NANC];
    __shared__ float aarea[NANC];
    __shared__ unsigned long long wbest[BLK / 64];
    const int tid = threadIdx.x;
    if (blockIdx.x == 0) { // ws is 0xAA-poisoned each call
        if (tid < 8) acc[tid] = 0.f;
        if (tid == 8) *done = 0u;
    }
    const int bg = blockIdx.x >> 2;   // column (b*NG+g) 0..255
    const int slice = blockIdx.x & 3;
    if (tid < NANC) {
        const float* ap = anchors + tid * 9;
        const float4 v = make_float4(ap[0], ap[1], ap[2], ap[3]);
        anch4[tid] = v;
        aarea[tid] = (v.z - v.x + 1.f) * (v.w - v.y + 1.f);
    }
    __syncthreads();
    unsigned long long best = 0ull;
    if (gt_valid[bg]) {
        const float g0 = gt_boxes[bg * 4 + 0], g1 = gt_boxes[bg * 4 + 1];
        const float g2 = gt_boxes[bg * 4 + 2], g3 = gt_boxes[bg * 4 + 3];
        const float ag = (g2 - g0 + 1.f) * (g3 - g1 + 1.f);
        const int cend = (slice + 1) * CPS;
        for (int c = slice * CPS + tid; c < cend; c += BLK) {
            const float sx = (float)((c % FEAT_W) * STRIDEPX);
            const float sy = (float)((c / FEAT_W) * STRIDEPX);
            int a = c * NANC;
#pragma unroll 4
            for (int t = 0; t < NANC; ++t, ++a) {
                const float4 av = anch4[t];          // wave-uniform broadcast
                const float r0 = sx + av.x, r1 = sy + av.y;
                const float r2 = sx + av.z, r3 = sy + av.w;
                const float xx1 = fmaxf(r0, g0), yy1 = fmaxf(r1, g1);
                const float xx2 = fminf(r2, g2), yy2 = fminf(r3, g3);
                const float iw = fmaxf(xx2 - xx1 + 1.f, 0.f);
                const float ih = fmaxf(yy2 - yy1 + 1.f, 0.f);
                const float inter = iw * ih;
                const float iou =
                    inter * __builtin_amdgcn_rcpf(aarea[t] + ag - inter);
                const unsigned long long p =
                    ((unsigned long long)__float_as_uint(iou) << 32) |
                    (unsigned long long)(0xFFFFFFFFu - (unsigned)a);
                if (p > best) best = p;
            }
        }
    }
    for (int off = 32; off; off >>= 1) {
        unsigned long long o = __shfl_down(best, off, 64);
        if (o > best) best = o;
    }
    if ((tid & 63) == 0) wbest[tid >> 6] = best;
    __syncthreads();
    if (tid == 0) {
        for (int w = 1; w < BLK / 64; ++w)
            if (wbest[w] > best) best = wbest[w];
        colpart[blockIdx.x] = best; // layout: bg*4 + slice, unique writer
    }
}

// Row pass + loss. 256 blocks (1/CU), b = blk/CB, chunks c0 + k*CB (<=16).
// cls software-pipelined TWO chunks ahead. Unchanged from R9 (57 us,
// matched prediction).
__global__ __launch_bounds__(BLK) void k_main(
    const float* __restrict__ cls, const float* __restrict__ bbox_2d,
    const float* __restrict__ bbox_3d, const float* __restrict__ gt_boxes,
    const float* __restrict__ gt_3d, const int* __restrict__ gt_labels,
    const int* __restrict__ gt_valid, const float* __restrict__ anchors,
    const float* __restrict__ means, const float* __restrict__ stds,
    const unsigned long long* __restrict__ colpart, float* __restrict__ acc,
    unsigned* __restrict__ done, float* __restrict__ out) {
#pragma clang fp contract(off)
    __shared__ float ax0_s[NANC], ay0_s[NANC], ax1_s[NANC], ay1_s[NANC];
    __shared__ float anch9[NANC * 9];
    __shared__ float4 gtb4_s[NG];
    __shared__ float ags_s[NG];
    __shared__ float gt3_s[NG * 7];
    __shared__ int lbl_s[NG];
    __shared__ int bag_s[NG], forceg_s[NG];
    __shared__ float mean_s[11], rstd_s[11];
    __shared__ unsigned vmask_s;
    __shared__ float red[5][BLK / 64];
    __shared__ int fixmap[MAXSLOTS * BLK]; // 16 KB

    const int tid = threadIdx.x;
    const int b = blockIdx.x / CB;
    const int c0 = blockIdx.x % CB;

    // ---- staging ----
    for (int i = tid; i < NANC * 9; i += BLK) anch9[i] = anchors[i];
    if (tid < NANC) {
        const float* ap = anchors + tid * 9;
        ax0_s[tid] = ap[0]; ay0_s[tid] = ap[1];
        ax1_s[tid] = ap[2]; ay1_s[tid] = ap[3];
    }
    for (int i = tid; i < NG * 7; i += BLK) gt3_s[i] = gt_3d[b * NG * 7 + i];
    int myval = 0;
    if (tid < NG) {
        const float4 q = ((const float4*)gt_boxes)[b * NG + tid];
        gtb4_s[tid] = q;
        ags_s[tid] = (q.z - q.x + 1.f) * (q.w - q.y + 1.f);
        lbl_s[tid] = gt_labels[b * NG + tid];
        myval = gt_valid[b * NG + tid];
        unsigned long long p = colpart[(b * NG + tid) * NSLICE + 0];
        for (int s = 1; s < NSLICE; ++s) {
            const unsigned long long q2 = colpart[(b * NG + tid) * NSLICE + s];
            if (q2 > p) p = q2;
        }
        const float gbest = __uint_as_float((unsigned)(p >> 32));
        bag_s[tid] = myval ? (int)(0xFFFFFFFFu - (unsigned)(p & 0xFFFFFFFFull)) : 0;
        forceg_s[tid] = (myval && gbest >= 0.35f) ? 1 : 0;
    }
    unsigned long long bal = __ballot(tid < NG && myval);
    if (tid == 0) vmask_s = (unsigned)bal;
    if (tid < 11) { mean_s[tid] = means[tid]; rstd_s[tid] = 1.0f / stds[tid]; }
    const int nslots = (CHUNKS - 1 - c0) / CB + 1; // <= 16
    for (int i = tid; i < nslots * BLK; i += BLK) fixmap[i] = -1;
    __syncthreads();
    if (tid == 0) {
        // ascending-g serial build: last-update-wins for agt, OR for force
        // (exact jax .at[ba].set / .at[ba].max gather-before-scatter)
        for (int g = 0; g < NG; ++g) {
            const int ba = bag_s[g];
            const int cb = ba >> 8; // chunk index (BLK=256)
            if (cb % CB == c0) {
                const int k = (cb - c0) / CB;
                const int idx = k * BLK + (ba & 255);
                const int e = fixmap[idx];
                const int anyf = ((e >= 0) ? (e & 0x40000000) : 0) |
                                 (forceg_s[g] ? 0x40000000 : 0);
                const int code = forceg_s[g] ? g : 32; // 32 = keep agt_orig
                fixmap[idx] = anyf | code;
            }
        }
    }
    __syncthreads();
    const unsigned vmask = vmask_s;

    // ---- main loop (cls pipelined TWO chunks ahead) ----
    float sum_ce = 0.f, sum_act = 0.f, sum_fg = 0.f, sum_2d = 0.f, sum_3d = 0.f;
    const size_t bbase = (size_t)b * A_TOTAL;

    int chunk = c0;
    float4 cv0 = *(const float4*)(cls + (bbase + (size_t)chunk * BLK + tid) * NC);
    float4 cv1 = make_float4(0.f, 0.f, 0.f, 0.f);
    if (nslots > 1)
        cv1 = *(const float4*)(cls + (bbase + (size_t)(chunk + CB) * BLK + tid) * NC);

    for (int k = 0; k < nslots; ++k) {
        float4 cv2 = make_float4(0.f, 0.f, 0.f, 0.f);
        if (k + 2 < nslots)
            cv2 = *(const float4*)(cls +
                     (bbase + (size_t)(chunk + 2 * CB) * BLK + tid) * NC);

        const int a = chunk * BLK + tid;
        const int t = a % NANC;
        const int cell = a / NANC;
        const float sx = (float)((cell % FEAT_W) * STRIDEPX);
        const float sy = (float)((cell / FEAT_W) * STRIDEPX);
        const float r0 = sx + ax0_s[t], r1 = sy + ay0_s[t];
        const float r2 = sx + ax1_s[t], r3 = sy + ay1_s[t];
        const float ar = (r2 - r0 + 1.f) * (r3 - r1 + 1.f);

        // grouped argmax: 4 groups of 8, scalar regs; strict '>' ascending
        // preserves first-occurrence exactly (incl. all-invalid -> 0)
        float m0 = -1.f, m1 = -1.f, m2 = -1.f, m3 = -1.f;
        int i0 = 0, i1 = 8, i2 = 16, i3 = 24;
#pragma unroll
        for (int g = 0; g < NG; ++g) {
            const float4 q = gtb4_s[g];              // wave-uniform broadcast
            const float xx1 = fmaxf(r0, q.x), yy1 = fmaxf(r1, q.y);
            const float xx2 = fminf(r2, q.z), yy2 = fminf(r3, q.w);
            const float iw = fmaxf(xx2 - xx1 + 1.f, 0.f);
            const float ih = fmaxf(yy2 - yy1 + 1.f, 0.f);
            const float inter = iw * ih;
            float iou = inter * __builtin_amdgcn_rcpf(ar + ags_s[g] - inter);
            iou = ((vmask >> g) & 1u) ? iou : -1.0f;
            if (g < 8)       { if (iou > m0) { m0 = iou; i0 = g; } }
            else if (g < 16) { if (iou > m1) { m1 = iou; i1 = g; } }
            else if (g < 24) { if (iou > m2) { m2 = iou; i2 = g; } }
            else             { if (iou > m3) { m3 = iou; i3 = g; } }
        }
        float best = m0; int agt = i0;
        if (m1 > best) { best = m1; agt = i1; }
        if (m2 > best) { best = m2; agt = i2; }
        if (m3 > best) { best = m3; agt = i3; }

        bool fg = best >= 0.5f;
        const int agt_orig = agt;
        const int f = fixmap[k * BLK + tid];
        if (f >= 0) {
            if (f & 0x40000000) fg = true;
            const int code = f & 63;
            agt = (code == 32) ? agt_orig : code;
        }
        const bool bgm = (!fg) && (best < 0.5f) && (best >= 0.0f);
        const float active = (fg || bgm) ? 1.f : 0.f;
        const int lbl = fg ? lbl_s[agt] : 0;

        const float mx = fmaxf(fmaxf(cv0.x, cv0.y), fmaxf(cv0.z, cv0.w));
        const float se = __expf(cv0.x - mx) + __expf(cv0.y - mx) +
                         __expf(cv0.z - mx) + __expf(cv0.w - mx);
        const float lse = mx + __logf(se);
        const float csel = (lbl == 0) ? cv0.x : (lbl == 1) ? cv0.y
                         : (lbl == 2) ? cv0.z : cv0.w;
        sum_ce += (lse - csel) * active;
        sum_act += active;

        if (fg) { // rare: exec-masked gathers, issued only when needed
            sum_fg += 1.f;
            const float w = r2 - r0 + 1.f, h = r3 - r1 + 1.f;
            const float rw = __builtin_amdgcn_rcpf(w);
            const float rh = __builtin_amdgcn_rcpf(h);
            const float cx = r0 + 0.5f * w, cy = r1 + 0.5f * h;
            const float4 Gq = gtb4_s[agt];
            const float gw = Gq.z - Gq.x + 1.f, gh = Gq.w - Gq.y + 1.f;
            const float gcx = Gq.x + 0.5f * gw, gcy = Gq.y + 0.5f * gh;
            float t2[4];
            t2[0] = (gcx - cx) * rw;
            t2[1] = (gcy - cy) * rh;
            t2[2] = __logf(gw * rw);
            t2[3] = __logf(gh * rh);
            const float4 b2 = *(const float4*)(bbox_2d + (bbase + a) * 4);
            const float b2v[4] = {b2.x, b2.y, b2.z, b2.w};
            float l2 = 0.f;
            for (int j = 0; j < 4; ++j)
                l2 += smooth_l1(b2v[j] - (t2[j] - mean_s[j]) * rstd_s[j]);
            sum_2d += l2;
            const float* q3p = &gt3_s[agt * 7];
            const float* b3 = bbox_3d + (bbase + a) * 7;
            float t3[7];
            t3[0] = (q3p[0] - cx) * rw;
            t3[1] = (q3p[1] - cy) * rh;
            t3[2] = q3p[2] - anch9[t * 9 + 4];
            t3[3] = __logf(q3p[3] * __builtin_amdgcn_rcpf(anch9[t * 9 + 5]));
            t3[4] = __logf(q3p[4] * __builtin_amdgcn_rcpf(anch9[t * 9 + 6]));
            t3[5] = __logf(q3p[5] * __builtin_amdgcn_rcpf(anch9[t * 9 + 7]));
            t3[6] = q3p[6] - anch9[t * 9 + 8];
            float l3 = 0.f;
            for (int j = 0; j < 7; ++j)
                l3 += smooth_l1(b3[j] - (t3[j] - mean_s[4 + j]) * rstd_s[4 + j]);
            sum_3d += l3;
        }
        cv0 = cv1;
        cv1 = cv2;
        chunk += CB;
    }

    // ---- block reduce -> 5 atomics; last block finishes ----
    float vals[5] = {sum_ce, sum_act, sum_fg, sum_2d, sum_3d};
#pragma unroll
    for (int j = 0; j < 5; ++j) {
        float v = vals[j];
        for (int off = 32; off; off >>= 1) v += __shfl_down(v, off, 64);
        if ((tid & 63) == 0) red[j][tid >> 6] = v;
    }
    __syncthreads();
    if (tid == 0) {
        for (int j = 0; j < 5; ++j) {
            float s = 0.f;
            for (int w = 0; w < BLK / 64; ++w) s += red[j][w];
            atomicAdd(&acc[j], s);
        }
        __threadfence();
        const unsigned old = atomicAdd(done, 1u);
        if (old == G2 - 1) {
            const float a0 = atomicAdd(&acc[0], 0.f);
            const float a1 = atomicAdd(&acc[1], 0.f);
            const float a2 = atomicAdd(&acc[2], 0.f);
            const float a3 = atomicAdd(&acc[3], 0.f);
            const float a4 = atomicAdd(&acc[4], 0.f);
            const float nact = fmaxf(a1, 1.f);
            const float nfg = fmaxf(a2, 1.f);
            out[0] = a0 / nact + a3 / nfg + a4 / nfg;
        }
    }
}

extern "C" void kernel_launch(void* const* d_in, const int* in_sizes, int n_in,
                              void* d_out, int out_size, void* d_ws, size_t ws_size,
                              hipStream_t stream) {
    const float* cls      = (const float*)d_in[0];
    const float* bbox_2d  = (const float*)d_in[1];
    const float* bbox_3d  = (const float*)d_in[2];
    const float* gt_boxes = (const float*)d_in[3];
    const float* gt_3d    = (const float*)d_in[4];
    const int*   gt_labels= (const int*)d_in[5];
    const int*   gt_valid = (const int*)d_in[6];
    const float* anchors  = (const float*)d_in[7];
    const float* means    = (const float*)d_in[8];
    const float* stds     = (const float*)d_in[9];

    unsigned long long* colpart = (unsigned long long*)d_ws;  // 8 KB @0
    float* acc = (float*)((char*)d_ws + 8192);
    unsigned* done = (unsigned*)((char*)d_ws + 8192 + 32);
    float* out = (float*)d_out;

    k_colpass<<<GCOL, BLK, 0, stream>>>(gt_boxes, gt_valid, anchors,
                                        colpart, acc, done);
    k_main<<<G2, BLK, 0, stream>>>(cls, bbox_2d, bbox_3d, gt_boxes, gt_3d,
                                   gt_labels, gt_valid, anchors, means, stds,
                                   colpart, acc, done, out);
}

// Round 11
// 169.587 us; speedup vs baseline: 1.2900x; 1.0129x over previous
//
#include <hip/hip_runtime.h>

#define FEAT_H 32
#define FEAT_W 110
#define NCELL (FEAT_H * FEAT_W) /* 3520 */
#define STRIDEPX 16
#define NB 8
#define NG 32
#define NANC 36
#define NC 4
#define A_TOTAL (NCELL * NANC) /* 126720 */

#define CBLK 1024            /* colpass: 256 blocks x 1024 thr = 16 waves/CU */
#define BLK 512              /* k_main: 256 blocks x 512 thr = 8 waves/CU */
#define CHK 512              /* anchors per chunk (= BLK) */
#define NCHK 248             /* ceil(A_TOTAL/CHK); last chunk partial */
#define G2 256
#define CB (G2 / NB)         /* 32 chunk stride per image */
#define MAXSLOTS 8           /* ceil(NCHK/CB) */

__device__ __forceinline__ float smooth_l1(float x) {
    float ax = fabsf(x);
    return ax < 1.f ? 0.5f * ax * ax : ax - 0.5f;
}

// ws: colpart[256] u64 @0 (2 KB), acc[8] f32 @8192, done u32 @8224.

// Column-max pass: ONE block per (b,g) column, 1024 threads (16 waves/CU —
// same waves/CU as the old 1024x256 version, 768 fewer blocks; blocks cost
// ~47 ns each in dispatch serialization). Cell-major: anch reads are
// wave-uniform broadcasts. Zeroes acc/done. Packed (iou<<32|~a) max = exact
// first-occurrence argmax.
__global__ __launch_bounds__(CBLK) void k_colpass(
    const float* __restrict__ gt_boxes, const int* __restrict__ gt_valid,
    const float* __restrict__ anchors, unsigned long long* __restrict__ colpart,
    float* __restrict__ acc, unsigned* __restrict__ done) {
#pragma clang fp contract(off)
    __shared__ float4 anch4[NANC];
    __shared__ float aarea[NANC];
    __shared__ unsigned long long wbest[CBLK / 64];
    const int tid = threadIdx.x;
    const int bg = blockIdx.x; // column (b*NG+g), 0..255
    if (bg == 0) { // ws is 0xAA-poisoned each call
        if (tid < 8) acc[tid] = 0.f;
        if (tid == 8) *done = 0u;
    }
    if (tid < NANC) {
        const float* ap = anchors + tid * 9;
        const float4 v = make_float4(ap[0], ap[1], ap[2], ap[3]);
        anch4[tid] = v;
        aarea[tid] = (v.z - v.x + 1.f) * (v.w - v.y + 1.f);
    }
    __syncthreads();
    unsigned long long best = 0ull;
    if (gt_valid[bg]) {
        const float g0 = gt_boxes[bg * 4 + 0], g1 = gt_boxes[bg * 4 + 1];
        const float g2 = gt_boxes[bg * 4 + 2], g3 = gt_boxes[bg * 4 + 3];
        const float ag = (g2 - g0 + 1.f) * (g3 - g1 + 1.f);
        for (int c = tid; c < NCELL; c += CBLK) {
            const float sx = (float)((c % FEAT_W) * STRIDEPX);
            const float sy = (float)((c / FEAT_W) * STRIDEPX);
            int a = c * NANC;
#pragma unroll 4
            for (int t = 0; t < NANC; ++t, ++a) {
                const float4 av = anch4[t];          // wave-uniform broadcast
                const float r0 = sx + av.x, r1 = sy + av.y;
                const float r2 = sx + av.z, r3 = sy + av.w;
                const float xx1 = fmaxf(r0, g0), yy1 = fmaxf(r1, g1);
                const float xx2 = fminf(r2, g2), yy2 = fminf(r3, g3);
                const float iw = fmaxf(xx2 - xx1 + 1.f, 0.f);
                const float ih = fmaxf(yy2 - yy1 + 1.f, 0.f);
                const float inter = iw * ih;
                const float iou =
                    inter * __builtin_amdgcn_rcpf(aarea[t] + ag - inter);
                const unsigned long long p =
                    ((unsigned long long)__float_as_uint(iou) << 32) |
                    (unsigned long long)(0xFFFFFFFFu - (unsigned)a);
                if (p > best) best = p;
            }
        }
    }
    for (int off = 32; off; off >>= 1) {
        unsigned long long o = __shfl_down(best, off, 64);
        if (o > best) best = o;
    }
    if ((tid & 63) == 0) wbest[tid >> 6] = best;
    __syncthreads();
    if (tid == 0) {
        for (int w = 1; w < CBLK / 64; ++w)
            if (wbest[w] > best) best = wbest[w];
        colpart[bg] = best; // unique writer, no slice merge needed downstream
    }
}

// Row pass + loss. 256 blocks x 512 threads (8 waves/CU), b = blk/CB,
// chunks c0 + k*CB (<= 8). cls pipelined two chunks ahead. CHK=512 leaves a
// partial tail chunk -> 'live' guard on the last chunk's upper lanes.
__global__ __launch_bounds__(BLK) void k_main(
    const float* __restrict__ cls, const float* __restrict__ bbox_2d,
    const float* __restrict__ bbox_3d, const float* __restrict__ gt_boxes,
    const float* __restrict__ gt_3d, const int* __restrict__ gt_labels,
    const int* __restrict__ gt_valid, const float* __restrict__ anchors,
    const float* __restrict__ means, const float* __restrict__ stds,
    const unsigned long long* __restrict__ colpart, float* __restrict__ acc,
    unsigned* __restrict__ done, float* __restrict__ out) {
#pragma clang fp contract(off)
    __shared__ float ax0_s[NANC], ay0_s[NANC], ax1_s[NANC], ay1_s[NANC];
    __shared__ float anch9[NANC * 9];
    __shared__ float4 gtb4_s[NG];
    __shared__ float ags_s[NG];
    __shared__ float gt3_s[NG * 7];
    __shared__ int lbl_s[NG];
    __shared__ int bag_s[NG], forceg_s[NG];
    __shared__ float mean_s[11], rstd_s[11];
    __shared__ unsigned vmask_s;
    __shared__ float red[5][BLK / 64];
    __shared__ int fixmap[MAXSLOTS * BLK]; // 16 KB

    const int tid = threadIdx.x;
    const int b = blockIdx.x / CB;
    const int c0 = blockIdx.x % CB;

    // ---- staging ----
    for (int i = tid; i < NANC * 9; i += BLK) anch9[i] = anchors[i];
    if (tid < NANC) {
        const float* ap = anchors + tid * 9;
        ax0_s[tid] = ap[0]; ay0_s[tid] = ap[1];
        ax1_s[tid] = ap[2]; ay1_s[tid] = ap[3];
    }
    for (int i = tid; i < NG * 7; i += BLK) gt3_s[i] = gt_3d[b * NG * 7 + i];
    int myval = 0;
    if (tid < NG) {
        const float4 q = ((const float4*)gt_boxes)[b * NG + tid];
        gtb4_s[tid] = q;
        ags_s[tid] = (q.z - q.x + 1.f) * (q.w - q.y + 1.f);
        lbl_s[tid] = gt_labels[b * NG + tid];
        myval = gt_valid[b * NG + tid];
        const unsigned long long p = colpart[b * NG + tid];
        const float gbest = __uint_as_float((unsigned)(p >> 32));
        bag_s[tid] = myval ? (int)(0xFFFFFFFFu - (unsigned)(p & 0xFFFFFFFFull)) : 0;
        forceg_s[tid] = (myval && gbest >= 0.35f) ? 1 : 0;
    }
    unsigned long long bal = __ballot(tid < NG && myval);
    if (tid == 0) vmask_s = (unsigned)bal;
    if (tid < 11) { mean_s[tid] = means[tid]; rstd_s[tid] = 1.0f / stds[tid]; }
    const int nslots = (NCHK - 1 - c0) / CB + 1; // 7 or 8
    for (int i = tid; i < nslots * BLK; i += BLK) fixmap[i] = -1;
    __syncthreads();
    if (tid == 0) {
        // ascending-g serial build: last-update-wins for agt, OR for force
        // (exact jax .at[ba].set / .at[ba].max gather-before-scatter)
        for (int g = 0; g < NG; ++g) {
            const int ba = bag_s[g];
            const int cb = ba >> 9; // chunk index (CHK=512)
            if (cb % CB == c0) {
                const int k = (cb - c0) / CB;
                const int idx = k * BLK + (ba & (CHK - 1));
                const int e = fixmap[idx];
                const int anyf = ((e >= 0) ? (e & 0x40000000) : 0) |
                                 (forceg_s[g] ? 0x40000000 : 0);
                const int code = forceg_s[g] ? g : 32; // 32 = keep agt_orig
                fixmap[idx] = anyf | code;
            }
        }
    }
    __syncthreads();
    const unsigned vmask = vmask_s;

    // ---- main loop (cls pipelined TWO chunks ahead) ----
    float sum_ce = 0.f, sum_act = 0.f, sum_fg = 0.f, sum_2d = 0.f, sum_3d = 0.f;
    const size_t bbase = (size_t)b * A_TOTAL;

    int chunk = c0;
    {
    }
    int a0i = chunk * CHK + tid;
    int ae = a0i < A_TOTAL ? a0i : (A_TOTAL - 1);
    float4 cv0 = *(const float4*)(cls + (bbase + ae) * NC);
    float4 cv1 = make_float4(0.f, 0.f, 0.f, 0.f);
    if (nslots > 1) {
        int a1i = (chunk + CB) * CHK + tid;
        int ae1 = a1i < A_TOTAL ? a1i : (A_TOTAL - 1);
        cv1 = *(const float4*)(cls + (bbase + ae1) * NC);
    }

    for (int k = 0; k < nslots; ++k) {
        float4 cv2 = make_float4(0.f, 0.f, 0.f, 0.f);
        if (k + 2 < nslots) {
            int a2i = (chunk + 2 * CB) * CHK + tid;
            int ae2 = a2i < A_TOTAL ? a2i : (A_TOTAL - 1);
            cv2 = *(const float4*)(cls + (bbase + ae2) * NC);
        }

        const int araw = chunk * CHK + tid;
        const bool live = araw < A_TOTAL;
        const int a = live ? araw : (A_TOTAL - 1); // clamped for safe math
        const int t = a % NANC;
        const int cell = a / NANC;
        const float sx = (float)((cell % FEAT_W) * STRIDEPX);
        const float sy = (float)((cell / FEAT_W) * STRIDEPX);
        const float r0 = sx + ax0_s[t], r1 = sy + ay0_s[t];
        const float r2 = sx + ax1_s[t], r3 = sy + ay1_s[t];
        const float ar = (r2 - r0 + 1.f) * (r3 - r1 + 1.f);

        // grouped argmax: 4 groups of 8, scalar regs; strict '>' ascending
        // preserves first-occurrence exactly (incl. all-invalid -> 0)
        float m0 = -1.f, m1 = -1.f, m2 = -1.f, m3 = -1.f;
        int i0 = 0, i1 = 8, i2 = 16, i3 = 24;
#pragma unroll
        for (int g = 0; g < NG; ++g) {
            const float4 q = gtb4_s[g];              // wave-uniform broadcast
            const float xx1 = fmaxf(r0, q.x), yy1 = fmaxf(r1, q.y);
            const float xx2 = fminf(r2, q.z), yy2 = fminf(r3, q.w);
            const float iw = fmaxf(xx2 - xx1 + 1.f, 0.f);
            const float ih = fmaxf(yy2 - yy1 + 1.f, 0.f);
            const float inter = iw * ih;
            float iou = inter * __builtin_amdgcn_rcpf(ar + ags_s[g] - inter);
            iou = ((vmask >> g) & 1u) ? iou : -1.0f;
            if (g < 8)       { if (iou > m0) { m0 = iou; i0 = g; } }
            else if (g < 16) { if (iou > m1) { m1 = iou; i1 = g; } }
            else if (g < 24) { if (iou > m2) { m2 = iou; i2 = g; } }
            else             { if (iou > m3) { m3 = iou; i3 = g; } }
        }
        float best = m0; int agt = i0;
        if (m1 > best) { best = m1; agt = i1; }
        if (m2 > best) { best = m2; agt = i2; }
        if (m3 > best) { best = m3; agt = i3; }

        bool fg = best >= 0.5f;
        const int agt_orig = agt;
        const int f = fixmap[k * BLK + tid];
        if (f >= 0) {
            if (f & 0x40000000) fg = true;
            const int code = f & 63;
            agt = (code == 32) ? agt_orig : code;
        }
        if (!live) fg = false; // tail lanes contribute nothing
        const bool bgm = live && (!fg) && (best < 0.5f) && (best >= 0.0f);
        const float active = (fg || bgm) ? 1.f : 0.f;
        const int lbl = fg ? lbl_s[agt] : 0;

        const float mx = fmaxf(fmaxf(cv0.x, cv0.y), fmaxf(cv0.z, cv0.w));
        const float se = __expf(cv0.x - mx) + __expf(cv0.y - mx) +
                         __expf(cv0.z - mx) + __expf(cv0.w - mx);
        const float lse = mx + __logf(se);
        const float csel = (lbl == 0) ? cv0.x : (lbl == 1) ? cv0.y
                         : (lbl == 2) ? cv0.z : cv0.w;
        sum_ce += (lse - csel) * active;
        sum_act += active;

        if (fg) { // rare: exec-masked gathers, issued only when needed
            sum_fg += 1.f;
            const float w = r2 - r0 + 1.f, h = r3 - r1 + 1.f;
            const float rw = __builtin_amdgcn_rcpf(w);
            const float rh = __builtin_amdgcn_rcpf(h);
            const float cx = r0 + 0.5f * w, cy = r1 + 0.5f * h;
            const float4 Gq = gtb4_s[agt];
            const float gw = Gq.z - Gq.x + 1.f, gh = Gq.w - Gq.y + 1.f;
            const float gcx = Gq.x + 0.5f * gw, gcy = Gq.y + 0.5f * gh;
            float t2[4];
            t2[0] = (gcx - cx) * rw;
            t2[1] = (gcy - cy) * rh;
            t2[2] = __logf(gw * rw);
            t2[3] = __logf(gh * rh);
            const float4 b2 = *(const float4*)(bbox_2d + (bbase + a) * 4);
            const float b2v[4] = {b2.x, b2.y, b2.z, b2.w};
            float l2 = 0.f;
            for (int j = 0; j < 4; ++j)
                l2 += smooth_l1(b2v[j] - (t2[j] - mean_s[j]) * rstd_s[j]);
            sum_2d += l2;
            const float* q3p = &gt3_s[agt * 7];
            const float* b3 = bbox_3d + (bbase + a) * 7;
            float t3[7];
            t3[0] = (q3p[0] - cx) * rw;
            t3[1] = (q3p[1] - cy) * rh;
            t3[2] = q3p[2] - anch9[t * 9 + 4];
            t3[3] = __logf(q3p[3] * __builtin_amdgcn_rcpf(anch9[t * 9 + 5]));
            t3[4] = __logf(q3p[4] * __builtin_amdgcn_rcpf(anch9[t * 9 + 6]));
            t3[5] = __logf(q3p[5] * __builtin_amdgcn_rcpf(anch9[t * 9 + 7]));
            t3[6] = q3p[6] - anch9[t * 9 + 8];
            float l3 = 0.f;
            for (int j = 0; j < 7; ++j)
                l3 += smooth_l1(b3[j] - (t3[j] - mean_s[4 + j]) * rstd_s[4 + j]);
            sum_3d += l3;
        }
        cv0 = cv1;
        cv1 = cv2;
        chunk += CB;
    }

    // ---- block reduce -> 5 atomics; last block finishes ----
    float vals[5] = {sum_ce, sum_act, sum_fg, sum_2d, sum_3d};
#pragma unroll
    for (int j = 0; j < 5; ++j) {
        float v = vals[j];
        for (int off = 32; off; off >>= 1) v += __shfl_down(v, off, 64);
        if ((tid & 63) == 0) red[j][tid >> 6] = v;
    }
    __syncthreads();
    if (tid == 0) {
        for (int j = 0; j < 5; ++j) {
            float s = 0.f;
            for (int w = 0; w < BLK / 64; ++w) s += red[j][w];
            atomicAdd(&acc[j], s);
        }
        __threadfence();
        const unsigned old = atomicAdd(done, 1u);
        if (old == G2 - 1) {
            const float a0 = atomicAdd(&acc[0], 0.f);
            const float a1 = atomicAdd(&acc[1], 0.f);
            const float a2 = atomicAdd(&acc[2], 0.f);
            const float a3 = atomicAdd(&acc[3], 0.f);
            const float a4 = atomicAdd(&acc[4], 0.f);
            const float nact = fmaxf(a1, 1.f);
            const float nfg = fmaxf(a2, 1.f);
            out[0] = a0 / nact + a3 / nfg + a4 / nfg;
        }
    }
}

extern "C" void kernel_launch(void* const* d_in, const int* in_sizes, int n_in,
                              void* d_out, int out_size, void* d_ws, size_t ws_size,
                              hipStream_t stream) {
    const float* cls      = (const float*)d_in[0];
    const float* bbox_2d  = (const float*)d_in[1];
    const float* bbox_3d  = (const float*)d_in[2];
    const float* gt_boxes = (const float*)d_in[3];
    const float* gt_3d    = (const float*)d_in[4];
    const int*   gt_labels= (const int*)d_in[5];
    const int*   gt_valid = (const int*)d_in[6];
    const float* anchors  = (const float*)d_in[7];
    const float* means    = (const float*)d_in[8];
    const float* stds     = (const float*)d_in[9];

    unsigned long long* colpart = (unsigned long long*)d_ws;  // 2 KB @0
    float* acc = (float*)((char*)d_ws + 8192);
    unsigned* done = (unsigned*)((char*)d_ws + 8192 + 32);
    float* out = (float*)d_out;

    k_colpass<<<NB * NG, CBLK, 0, stream>>>(gt_boxes, gt_valid, anchors,
                                            colpart, acc, done);
    k_main<<<G2, BLK, 0, stream>>>(cls, bbox_2d, bbox_3d, gt_boxes, gt_3d,
                                   gt_labels, gt_valid, anchors, means, stds,
                                   colpart, acc, done, out);
}